// Round 10
// baseline (325.465 us; speedup 1.0000x reference)
//
#include <hip/hip_runtime.h>
#include <hip/hip_bf16.h>

#define NN 50000
#define NE 600000
#define DD 128
#define NR 8
#define NB (NN * NR)                   // 400000 (dst,rel) bins
#define NCHUNK8 ((NB + 255) / 256)     // 1563 scan blocks
#define PERT ((NCHUNK8 + 255) / 256)   // 7 items/thread in bscan

typedef __attribute__((ext_vector_type(8))) short bf16x8;
typedef __attribute__((ext_vector_type(4))) float f32x4;

__device__ __forceinline__ unsigned short f2bf(float f) {
  __hip_bfloat16 h = __float2bfloat16(f);
  return *reinterpret_cast<unsigned short*>(&h);
}
__device__ __forceinline__ unsigned pk2(float lo, float hi) {
  return (unsigned)f2bf(lo) | ((unsigned)f2bf(hi) << 16);
}
__device__ __forceinline__ float bflo(unsigned u) { return __uint_as_float(u << 16); }
__device__ __forceinline__ float bfhi(unsigned u) { return __uint_as_float(u & 0xffff0000u); }

// ---------------- weight transpose+convert: WT[m][o][d] = bf16(W[m][d][o]) ----------------
__global__ __launch_bounds__(128) void convw_kernel(
    const float* __restrict__ W1, const float* __restrict__ Ws1,
    const float* __restrict__ W2, const float* __restrict__ Ws2,
    unsigned short* __restrict__ WT)
{
  const int m = blockIdx.y, o = blockIdx.x, d = threadIdx.x;
  const float* src;
  if (m < 8)       src = W1 + (size_t)m * DD * DD;
  else if (m == 8) src = Ws1;
  else if (m < 17) src = W2 + (size_t)(m - 9) * DD * DD;
  else             src = Ws2;
  WT[(size_t)m * DD * DD + o * DD + d] = f2bf(src[(size_t)d * DD + o]);
}

// ---------------- h0 = bf16(emb[node_ids]) ----------------
__global__ __launch_bounds__(256) void convh_kernel(
    const float* __restrict__ emb, const int* __restrict__ ids,
    unsigned short* __restrict__ h)
{
  const int gid = blockIdx.x * 256 + threadIdx.x;   // NN*16 total
  if (gid >= NN * 16) return;
  const int row = gid >> 4;
  const int off = (gid & 15) * 8;
  const int srcRow = ids[row];
  const float* src = emb + (size_t)srcRow * DD + off;
  const float4 a = *reinterpret_cast<const float4*>(src);
  const float4 b = *reinterpret_cast<const float4*>(src + 4);
  uint4 u;
  u.x = pk2(a.x, a.y); u.y = pk2(a.z, a.w);
  u.z = pk2(b.x, b.y); u.w = pk2(b.z, b.w);
  *reinterpret_cast<uint4*>(h + (size_t)row * DD + off) = u;
}

// ---------------- CSR build over (dst,rel) bins ----------------
__global__ __launch_bounds__(256) void hist_kernel(
    const int* __restrict__ dst, const int* __restrict__ et,
    int* __restrict__ deg)
{
  const int e = blockIdx.x * 256 + threadIdx.x;
  if (e < NE) atomicAdd(&deg[dst[e] * NR + et[e]], 1);
}

__global__ __launch_bounds__(256) void bsum_kernel(
    const int* __restrict__ deg, int* __restrict__ bsum)
{
  __shared__ int tmp[256];
  const int t = threadIdx.x;
  const int i = blockIdx.x * 256 + t;
  tmp[t] = (i < NB) ? deg[i] : 0;
  __syncthreads();
#pragma unroll
  for (int off = 128; off > 0; off >>= 1) {
    if (t < off) tmp[t] += tmp[t + off];
    __syncthreads();
  }
  if (t == 0) bsum[blockIdx.x] = tmp[0];
}

// 1 block: exclusive scan of bsum[NCHUNK8] -> bbase[NCHUNK8]; 7 items/thread
__global__ __launch_bounds__(256) void bscan_kernel(
    const int* __restrict__ bsum, int* __restrict__ bbase)
{
  __shared__ int tmp[256];
  const int t = threadIdx.x;
  const int b = t * PERT;
  const int e = min(b + PERT, NCHUNK8);
  int s = 0;
  for (int i = b; i < e; ++i) s += bsum[i];
  tmp[t] = s;
  __syncthreads();
#pragma unroll
  for (int off = 1; off < 256; off <<= 1) {
    const int x = (t >= off) ? tmp[t - off] : 0;
    __syncthreads();
    tmp[t] += x;
    __syncthreads();
  }
  int run = tmp[t] - s;        // exclusive base of this thread's chunk
  for (int i = b; i < e; ++i) {
    const int v = bsum[i];
    bbase[i] = run;
    run += v;
  }
}

__global__ __launch_bounds__(256) void expand_kernel(
    int* deg, const int* __restrict__ bbase, int* __restrict__ offsets)
{
  __shared__ int tmp[256];
  const int t = threadIdx.x;
  const int i = blockIdx.x * 256 + t;
  const int v = (i < NB) ? deg[i] : 0;
  tmp[t] = v;
  __syncthreads();
#pragma unroll
  for (int off = 1; off < 256; off <<= 1) {
    const int x = (t >= off) ? tmp[t - off] : 0;
    __syncthreads();
    tmp[t] += x;
    __syncthreads();
  }
  const int base = bbase[blockIdx.x];
  const int excl = base + tmp[t] - v;
  if (i < NB) {
    offsets[i] = excl;
    deg[i] = excl;                  // fill cursor
    if (i == NB - 1) offsets[NB] = base + tmp[t];
  }
}

// eidx[pos] = src, bucketed by (dst,rel)
__global__ __launch_bounds__(256) void fill_kernel(
    const int* __restrict__ src, const int* __restrict__ dst,
    const int* __restrict__ et, int* __restrict__ cursor,
    int* __restrict__ eidx)
{
  const int e = blockIdx.x * 256 + threadIdx.x;
  if (e < NE) {
    const int pos = atomicAdd(&cursor[dst[e] * NR + et[e]], 1);
    eidx[pos] = src[e];
  }
}

// ---------------- h-space aggregation: one wave per (dst,rel) bin ----------------
// lane owns 2 cols; s[bin][:] = sum of h[src] over the bin's edges (0 if empty)
__global__ __launch_bounds__(256) void agg_kernel(
    const unsigned short* __restrict__ h,
    const int* __restrict__ off8, const int* __restrict__ eidx,
    unsigned short* __restrict__ s)
{
  const int bin = blockIdx.x * 4 + (threadIdx.x >> 6);   // grid covers NB exactly
  const int lane = threadIdx.x & 63;
  const int beg = off8[bin];
  const int end = off8[bin + 1];
  const unsigned short* hp = h + lane * 2;

  float ax = 0.f, ay = 0.f;
  int e = beg;
  for (; e + 3 < end; e += 4) {
    const int s0 = eidx[e], s1 = eidx[e + 1], s2 = eidx[e + 2], s3 = eidx[e + 3];
    const unsigned u0 = *reinterpret_cast<const unsigned*>(hp + (size_t)s0 * DD);
    const unsigned u1 = *reinterpret_cast<const unsigned*>(hp + (size_t)s1 * DD);
    const unsigned u2 = *reinterpret_cast<const unsigned*>(hp + (size_t)s2 * DD);
    const unsigned u3 = *reinterpret_cast<const unsigned*>(hp + (size_t)s3 * DD);
    ax += (bflo(u0) + bflo(u1)) + (bflo(u2) + bflo(u3));
    ay += (bfhi(u0) + bfhi(u1)) + (bfhi(u2) + bfhi(u3));
  }
  for (; e < end; ++e) {
    const unsigned u0 = *reinterpret_cast<const unsigned*>(hp + (size_t)eidx[e] * DD);
    ax += bflo(u0);
    ay += bfhi(u0);
  }

  *reinterpret_cast<unsigned*>(s + (size_t)bin * DD + lane * 2) = pk2(ax, ay);
}

// ---------------- fused GEMM: out[n] = sum_r s[n,r]@W_r + h[n]@Wself + b ----------------
template<int OUTF32>
__global__ __launch_bounds__(256) void gemm_kernel(
    const unsigned short* __restrict__ hbuf,   // [NN][128] self input (bf16)
    const unsigned short* __restrict__ s,      // [NN][8][128] (bf16)
    const unsigned short* __restrict__ WTl,    // this layer: [9][128][128] bf16 [o][d]
    const float* __restrict__ bias,
    void* __restrict__ out)
{
  __shared__ __align__(16) char ldsW[2][DD * DD * 2];   // 2 x 32 KB, XOR-swizzled

  const int tid = threadIdx.x;
  const int rowBase = blockIdx.x * 128;
  const int lane = tid & 63;
  const int w = tid >> 6;
  const int c = lane & 15;
  const int g = lane >> 4;
  int nn[2], nld[2];
#pragma unroll
  for (int u = 0; u < 2; ++u) {
    nn[u] = rowBase + w * 32 + u * 16 + c;
    nld[u] = (nn[u] < NN) ? nn[u] : (NN - 1);
  }

  int srcOff[8];
#pragma unroll
  for (int j = 0; j < 8; ++j) {
    const int dstB = (tid + j * 256) * 16;
    const int srcB = dstB ^ (((dstB >> 8) & 7) << 4);
    srcOff[j] = srcB >> 1;
  }

  uint4 wreg[8];
#pragma unroll
  for (int j = 0; j < 8; ++j)
    wreg[j] = *reinterpret_cast<const uint4*>(WTl + srcOff[j]);
#pragma unroll
  for (int j = 0; j < 8; ++j)
    *reinterpret_cast<uint4*>(ldsW[0] + (tid + j * 256) * 16) = wreg[j];

  bf16x8 sfA[2][4], sfB[2][4];
#pragma unroll
  for (int u = 0; u < 2; ++u) {
    const unsigned short* p0 = s + (size_t)nld[u] * (NR * DD);
#pragma unroll
    for (int ks = 0; ks < 4; ++ks)
      sfA[u][ks] = *reinterpret_cast<const bf16x8*>(p0 + ks * 32 + g * 8);
  }

  f32x4 acc[2][8];
#pragma unroll
  for (int u = 0; u < 2; ++u)
#pragma unroll
    for (int t = 0; t < 8; ++t) acc[u][t] = (f32x4){0.f, 0.f, 0.f, 0.f};

#define GSTEP(R, CUR, NXT)                                                            \
  {                                                                                   \
    __syncthreads();                                                                  \
    const char* buf = ldsW[(R) & 1];                                                  \
    if ((R) < NR) {                                                                   \
      const unsigned short* wnext = WTl + (size_t)((R) + 1) * DD * DD;                \
      _Pragma("unroll")                                                               \
      for (int j = 0; j < 8; ++j)                                                     \
        wreg[j] = *reinterpret_cast<const uint4*>(wnext + srcOff[j]);                 \
      _Pragma("unroll")                                                               \
      for (int u = 0; u < 2; ++u) {                                                   \
        const unsigned short* pn = ((R) + 1 < NR)                                     \
            ? s + (size_t)nld[u] * (NR * DD) + ((R) + 1) * DD                         \
            : hbuf + (size_t)nld[u] * DD;                                             \
        _Pragma("unroll")                                                             \
        for (int ks = 0; ks < 4; ++ks)                                                \
          NXT[u][ks] = *reinterpret_cast<const bf16x8*>(pn + ks * 32 + g * 8);        \
      }                                                                               \
    }                                                                                 \
    _Pragma("unroll")                                                                 \
    for (int ks = 0; ks < 4; ++ks) {                                                  \
      _Pragma("unroll")                                                               \
      for (int t = 0; t < 8; ++t) {                                                   \
        const int addr = (((t * 16 + c) << 8) + (ks << 6) + (g << 4)) ^ ((c & 7) << 4); \
        bf16x8 a = *reinterpret_cast<const bf16x8*>(buf + addr);                      \
        acc[0][t] = __builtin_amdgcn_mfma_f32_16x16x32_bf16(a, CUR[0][ks], acc[0][t], 0, 0, 0); \
        acc[1][t] = __builtin_amdgcn_mfma_f32_16x16x32_bf16(a, CUR[1][ks], acc[1][t], 0, 0, 0); \
      }                                                                               \
    }                                                                                 \
    if ((R) < NR) {                                                                   \
      char* nbuf = ldsW[((R) & 1) ^ 1];                                               \
      _Pragma("unroll")                                                               \
      for (int j = 0; j < 8; ++j)                                                     \
        *reinterpret_cast<uint4*>(nbuf + (tid + j * 256) * 16) = wreg[j];             \
    }                                                                                 \
  }

  GSTEP(0, sfA, sfB) GSTEP(1, sfB, sfA) GSTEP(2, sfA, sfB) GSTEP(3, sfB, sfA)
  GSTEP(4, sfA, sfB) GSTEP(5, sfB, sfA) GSTEP(6, sfA, sfB) GSTEP(7, sfB, sfA)
  GSTEP(8, sfA, sfB)
#undef GSTEP

#pragma unroll
  for (int u = 0; u < 2; ++u) {
    const int n = nn[u];
    if (n >= NN) continue;
    if (OUTF32) {
      float* dst = (float*)out + (size_t)n * DD;
#pragma unroll
      for (int t = 0; t < 8; ++t) {
        const int o0 = t * 16 + g * 4;
        const float4 bv = *reinterpret_cast<const float4*>(bias + o0);
        float4 o;
        o.x = acc[u][t][0] + bv.x; o.y = acc[u][t][1] + bv.y;
        o.z = acc[u][t][2] + bv.z; o.w = acc[u][t][3] + bv.w;
        *reinterpret_cast<float4*>(dst + o0) = o;
      }
    } else {
      unsigned short* dst = (unsigned short*)out + (size_t)n * DD;
#pragma unroll
      for (int t = 0; t < 8; ++t) {
        const int o0 = t * 16 + g * 4;
        const float4 bv = *reinterpret_cast<const float4*>(bias + o0);
        uint2 q;
        q.x = pk2(acc[u][t][0] + bv.x, acc[u][t][1] + bv.y);
        q.y = pk2(acc[u][t][2] + bv.z, acc[u][t][3] + bv.w);
        *reinterpret_cast<uint2*>(dst + o0) = q;
      }
    }
  }
}

extern "C" void kernel_launch(void* const* d_in, const int* in_sizes, int n_in,
                              void* d_out, int out_size, void* d_ws, size_t ws_size,
                              hipStream_t stream) {
  const int*   node_ids = (const int*)d_in[0];
  const int*   src   = (const int*)d_in[1];
  const int*   dst   = (const int*)d_in[2];
  const int*   etype = (const int*)d_in[3];
  const float* emb   = (const float*)d_in[4];
  const float* W1    = (const float*)d_in[5];
  const float* Ws1   = (const float*)d_in[6];
  const float* b1    = (const float*)d_in[7];
  const float* W2    = (const float*)d_in[8];
  const float* Ws2   = (const float*)d_in[9];
  const float* b2    = (const float*)d_in[10];

  // ws layout (~121.5 MB):
  //   s      bf16 [NN*8*DD]      102.4 MB
  //   hbuf   bf16 [NN*DD]         12.8 MB
  //   WT     bf16 [18*DD*DD]       0.59 MB
  //   off8   i32  [NB+1]           1.6 MB
  //   deg8   i32  [NB]             1.6 MB
  //   eidx   i32  [NE]             2.4 MB
  //   bsum/bbase i32 [NCHUNK8]     12.5 KB
  char* p = (char*)d_ws;
  unsigned short* s    = (unsigned short*)p;  p += (size_t)NN * NR * DD * 2;
  unsigned short* hbuf = (unsigned short*)p;  p += (size_t)NN * DD * 2;
  unsigned short* WT   = (unsigned short*)p;  p += (size_t)18 * DD * DD * 2;
  int* off8            = (int*)p;             p += (size_t)(NB + 1) * 4;
  int* deg8            = (int*)p;             p += (size_t)NB * 4;
  int* eidx            = (int*)p;             p += (size_t)NE * 4;
  int* bsum            = (int*)p;             p += (size_t)NCHUNK8 * 4;
  int* bbase           = (int*)p;

  const int eb = (NE + 255) / 256;
  const int tb = (NN + 127) / 128;   // 391
  const int ab = NB / 4;             // 100000 (one wave per bin)

  // weight convert + h0 convert + CSR build over (dst,rel)
  convw_kernel<<<dim3(DD, 18), 128, 0, stream>>>(W1, Ws1, W2, Ws2, WT);
  convh_kernel<<<(NN * 16) / 256, 256, 0, stream>>>(emb, node_ids, hbuf);
  hipMemsetAsync(deg8, 0, (size_t)NB * 4, stream);
  hist_kernel<<<eb, 256, 0, stream>>>(dst, etype, deg8);
  bsum_kernel<<<NCHUNK8, 256, 0, stream>>>(deg8, bsum);
  bscan_kernel<<<1, 256, 0, stream>>>(bsum, bbase);
  expand_kernel<<<NCHUNK8, 256, 0, stream>>>(deg8, bbase, off8);
  fill_kernel<<<eb, 256, 0, stream>>>(src, dst, etype, deg8, eidx);

  // layer 1: s = agg(h0) ; h1 = [s|h0] @ W1stack + b1  (bf16, in-place into hbuf)
  agg_kernel<<<ab, 256, 0, stream>>>(hbuf, off8, eidx, s);
  gemm_kernel<0><<<tb, 256, 0, stream>>>(hbuf, s, WT, b1, hbuf);
  // layer 2: s = agg(h1) ; out = [s|h1] @ W2stack + b2  (f32)
  agg_kernel<<<ab, 256, 0, stream>>>(hbuf, off8, eidx, s);
  gemm_kernel<1><<<tb, 256, 0, stream>>>(hbuf, s, WT + (size_t)9 * DD * DD, b2, (float*)d_out);
}

// Round 11
// 258.092 us; speedup vs baseline: 1.2610x; 1.2610x over previous
//
#include <hip/hip_runtime.h>
#include <hip/hip_bf16.h>

#define NN 50000
#define NE 600000
#define DD 128
#define NR 8
#define NB (NN * NR)                   // 400000 (dst,rel) bins
#define NCHUNK8 ((NB + 255) / 256)     // 1563 scan blocks
#define PERT ((NCHUNK8 + 255) / 256)   // 7 items/thread in bscan

typedef __attribute__((ext_vector_type(8))) short bf16x8;
typedef __attribute__((ext_vector_type(4))) float f32x4;

__device__ __forceinline__ unsigned short f2bf(float f) {
  __hip_bfloat16 h = __float2bfloat16(f);
  return *reinterpret_cast<unsigned short*>(&h);
}
__device__ __forceinline__ unsigned pk2(float lo, float hi) {
  return (unsigned)f2bf(lo) | ((unsigned)f2bf(hi) << 16);
}
__device__ __forceinline__ float bflo(unsigned u) { return __uint_as_float(u << 16); }
__device__ __forceinline__ float bfhi(unsigned u) { return __uint_as_float(u & 0xffff0000u); }

// ---------------- weight transpose+convert: WT[m][o][d] = bf16(W[m][d][o]) ----------------
__global__ __launch_bounds__(128) void convw_kernel(
    const float* __restrict__ W1, const float* __restrict__ Ws1,
    const float* __restrict__ W2, const float* __restrict__ Ws2,
    unsigned short* __restrict__ WT)
{
  const int m = blockIdx.y, o = blockIdx.x, d = threadIdx.x;
  const float* src;
  if (m < 8)       src = W1 + (size_t)m * DD * DD;
  else if (m == 8) src = Ws1;
  else if (m < 17) src = W2 + (size_t)(m - 9) * DD * DD;
  else             src = Ws2;
  WT[(size_t)m * DD * DD + o * DD + d] = f2bf(src[(size_t)d * DD + o]);
}

// ---------------- h0 = bf16(emb[node_ids]) ----------------
__global__ __launch_bounds__(256) void convh_kernel(
    const float* __restrict__ emb, const int* __restrict__ ids,
    unsigned short* __restrict__ h)
{
  const int gid = blockIdx.x * 256 + threadIdx.x;   // NN*16 total
  if (gid >= NN * 16) return;
  const int row = gid >> 4;
  const int off = (gid & 15) * 8;
  const int srcRow = ids[row];
  const float* src = emb + (size_t)srcRow * DD + off;
  const float4 a = *reinterpret_cast<const float4*>(src);
  const float4 b = *reinterpret_cast<const float4*>(src + 4);
  uint4 u;
  u.x = pk2(a.x, a.y); u.y = pk2(a.z, a.w);
  u.z = pk2(b.x, b.y); u.w = pk2(b.z, b.w);
  *reinterpret_cast<uint4*>(h + (size_t)row * DD + off) = u;
}

// ---------------- CSR build over (dst,rel) bins ----------------
__global__ __launch_bounds__(256) void hist_kernel(
    const int* __restrict__ dst, const int* __restrict__ et,
    int* __restrict__ deg)
{
  const int e = blockIdx.x * 256 + threadIdx.x;
  if (e < NE) atomicAdd(&deg[dst[e] * NR + et[e]], 1);
}

__global__ __launch_bounds__(256) void bsum_kernel(
    const int* __restrict__ deg, int* __restrict__ bsum)
{
  __shared__ int tmp[256];
  const int t = threadIdx.x;
  const int i = blockIdx.x * 256 + t;
  tmp[t] = (i < NB) ? deg[i] : 0;
  __syncthreads();
#pragma unroll
  for (int off = 128; off > 0; off >>= 1) {
    if (t < off) tmp[t] += tmp[t + off];
    __syncthreads();
  }
  if (t == 0) bsum[blockIdx.x] = tmp[0];
}

// 1 block: exclusive scan of bsum[NCHUNK8] -> bbase[NCHUNK8]; 7 items/thread
__global__ __launch_bounds__(256) void bscan_kernel(
    const int* __restrict__ bsum, int* __restrict__ bbase)
{
  __shared__ int tmp[256];
  const int t = threadIdx.x;
  const int b = t * PERT;
  const int e = min(b + PERT, NCHUNK8);
  int s = 0;
  for (int i = b; i < e; ++i) s += bsum[i];
  tmp[t] = s;
  __syncthreads();
#pragma unroll
  for (int off = 1; off < 256; off <<= 1) {
    const int x = (t >= off) ? tmp[t - off] : 0;
    __syncthreads();
    tmp[t] += x;
    __syncthreads();
  }
  int run = tmp[t] - s;        // exclusive base of this thread's chunk
  for (int i = b; i < e; ++i) {
    const int v = bsum[i];
    bbase[i] = run;
    run += v;
  }
}

__global__ __launch_bounds__(256) void expand_kernel(
    int* deg, const int* __restrict__ bbase, int* __restrict__ offsets)
{
  __shared__ int tmp[256];
  const int t = threadIdx.x;
  const int i = blockIdx.x * 256 + t;
  const int v = (i < NB) ? deg[i] : 0;
  tmp[t] = v;
  __syncthreads();
#pragma unroll
  for (int off = 1; off < 256; off <<= 1) {
    const int x = (t >= off) ? tmp[t - off] : 0;
    __syncthreads();
    tmp[t] += x;
    __syncthreads();
  }
  const int base = bbase[blockIdx.x];
  const int excl = base + tmp[t] - v;
  if (i < NB) {
    offsets[i] = excl;
    deg[i] = excl;                  // fill cursor
    if (i == NB - 1) offsets[NB] = base + tmp[t];
  }
}

// eidx[pos] = src, bucketed by (dst,rel)
__global__ __launch_bounds__(256) void fill_kernel(
    const int* __restrict__ src, const int* __restrict__ dst,
    const int* __restrict__ et, int* __restrict__ cursor,
    int* __restrict__ eidx)
{
  const int e = blockIdx.x * 256 + threadIdx.x;
  if (e < NE) {
    const int pos = atomicAdd(&cursor[dst[e] * NR + et[e]], 1);
    eidx[pos] = src[e];
  }
}

// ---------------- gather-sum of h[src] slices -> MFMA B-fragment ----------------
__device__ __forceinline__ void gather_frag(
    const unsigned short* __restrict__ h,
    const int* __restrict__ eidx,
    int beg, int end, int g, bf16x8* frag)
{
  float s[4][8];
#pragma unroll
  for (int ks = 0; ks < 4; ++ks)
#pragma unroll
    for (int j = 0; j < 8; ++j) s[ks][j] = 0.f;
  for (int i = beg; i < end; ++i) {
    const int srcn = eidx[i];
    const unsigned short* hp = h + (size_t)srcn * DD + g * 8;
#pragma unroll
    for (int ks = 0; ks < 4; ++ks) {
      const uint4 q = *reinterpret_cast<const uint4*>(hp + ks * 32);
      s[ks][0] += bflo(q.x); s[ks][1] += bfhi(q.x);
      s[ks][2] += bflo(q.y); s[ks][3] += bfhi(q.y);
      s[ks][4] += bflo(q.z); s[ks][5] += bfhi(q.z);
      s[ks][6] += bflo(q.w); s[ks][7] += bfhi(q.w);
    }
  }
#pragma unroll
  for (int ks = 0; ks < 4; ++ks) {
    uint4 u;
    u.x = pk2(s[ks][0], s[ks][1]);
    u.y = pk2(s[ks][2], s[ks][3]);
    u.z = pk2(s[ks][4], s[ks][5]);
    u.w = pk2(s[ks][6], s[ks][7]);
    frag[ks] = *reinterpret_cast<bf16x8*>(&u);
  }
}

// ---------------- fused RGCN layer: gather + GEMM, no s round-trip ----------------
// block = 128 dst nodes (8 waves x 16); per relation r: gather h[src] sums into
// B-fragments in registers, MFMA vs W_r (LDS dbuf), then self + bias epilogue.
template<int OUTF32>
__global__ __launch_bounds__(512, 4) void layer_kernel(
    const unsigned short* __restrict__ h,      // [NN][128] bf16 (read-only)
    const int* __restrict__ off8, const int* __restrict__ eidx,
    const unsigned short* __restrict__ WTl,    // this layer: [9][128][128] bf16 [o][d]
    const float* __restrict__ bias,
    void* __restrict__ out)                    // [NN][128] bf16 or f32
{
  __shared__ __align__(16) char ldsW[2][DD * DD * 2];   // 2 x 32 KB, XOR-swizzled

  const int tid = threadIdx.x;
  const int rowBase = blockIdx.x * 128;
  const int lane = tid & 63;
  const int w = tid >> 6;            // 0..7
  const int c = lane & 15;           // n selector
  const int g = lane >> 4;           // k group
  const int n = rowBase + w * 16 + c;
  const int nld = (n < NN) ? n : (NN - 1);

  // staging geometry: dst linear 16B chunks, src pre-inverse-swizzled
  int srcOff[4];
#pragma unroll
  for (int j = 0; j < 4; ++j) {
    const int dstB = (tid + j * 512) * 16;
    const int srcB = dstB ^ (((dstB >> 8) & 7) << 4);
    srcOff[j] = srcB >> 1;
  }

  // prologue: W[0] -> LDS buf0 ; gather fragment for relation 0
  uint4 wreg[4];
#pragma unroll
  for (int j = 0; j < 4; ++j)
    wreg[j] = *reinterpret_cast<const uint4*>(WTl + srcOff[j]);
#pragma unroll
  for (int j = 0; j < 4; ++j)
    *reinterpret_cast<uint4*>(ldsW[0] + (tid + j * 512) * 16) = wreg[j];

  bf16x8 fA[4], fB[4];
  gather_frag(h, eidx, off8[nld * NR], off8[nld * NR + 1], g, fA);

  f32x4 acc[8];
#pragma unroll
  for (int t = 0; t < 8; ++t) acc[t] = (f32x4){0.f, 0.f, 0.f, 0.f};

#define LSTEP(R, CUR, NXT)                                                            \
  {                                                                                   \
    __syncthreads();                                                                  \
    const char* buf = ldsW[(R) & 1];                                                  \
    if ((R) < NR) {                                                                   \
      const unsigned short* wnext = WTl + (size_t)((R) + 1) * DD * DD;                \
      _Pragma("unroll")                                                               \
      for (int j = 0; j < 4; ++j)                                                     \
        wreg[j] = *reinterpret_cast<const uint4*>(wnext + srcOff[j]);                 \
    }                                                                                 \
    _Pragma("unroll")                                                                 \
    for (int ks = 0; ks < 4; ++ks) {                                                  \
      _Pragma("unroll")                                                               \
      for (int t = 0; t < 8; ++t) {                                                   \
        const int addr = (((t * 16 + c) << 8) + (ks << 6) + (g << 4)) ^ ((c & 7) << 4); \
        bf16x8 a = *reinterpret_cast<const bf16x8*>(buf + addr);                      \
        acc[t] = __builtin_amdgcn_mfma_f32_16x16x32_bf16(a, CUR[ks], acc[t], 0, 0, 0); \
      }                                                                               \
    }                                                                                 \
    if ((R) < NR) {                                                                   \
      if ((R) + 1 < NR) {                                                             \
        gather_frag(h, eidx, off8[nld * NR + (R) + 1], off8[nld * NR + (R) + 2], g, NXT); \
      } else {                                                                        \
        _Pragma("unroll")                                                             \
        for (int ks = 0; ks < 4; ++ks)                                                \
          NXT[ks] = *reinterpret_cast<const bf16x8*>(h + (size_t)nld * DD + ks * 32 + g * 8); \
      }                                                                               \
      char* nbuf = ldsW[((R) & 1) ^ 1];                                               \
      _Pragma("unroll")                                                               \
      for (int j = 0; j < 4; ++j)                                                     \
        *reinterpret_cast<uint4*>(nbuf + (tid + j * 512) * 16) = wreg[j];             \
    }                                                                                 \
  }

  LSTEP(0, fA, fB) LSTEP(1, fB, fA) LSTEP(2, fA, fB) LSTEP(3, fB, fA)
  LSTEP(4, fA, fB) LSTEP(5, fB, fA) LSTEP(6, fA, fB) LSTEP(7, fB, fA)
  LSTEP(8, fA, fB)
#undef LSTEP

  if (n >= NN) return;
  if (OUTF32) {
    float* dst = (float*)out + (size_t)n * DD;
#pragma unroll
    for (int t = 0; t < 8; ++t) {
      const int o0 = t * 16 + g * 4;
      const float4 bv = *reinterpret_cast<const float4*>(bias + o0);
      float4 o;
      o.x = acc[t][0] + bv.x; o.y = acc[t][1] + bv.y;
      o.z = acc[t][2] + bv.z; o.w = acc[t][3] + bv.w;
      *reinterpret_cast<float4*>(dst + o0) = o;
    }
  } else {
    unsigned short* dst = (unsigned short*)out + (size_t)n * DD;
#pragma unroll
    for (int t = 0; t < 8; ++t) {
      const int o0 = t * 16 + g * 4;
      const float4 bv = *reinterpret_cast<const float4*>(bias + o0);
      uint2 q;
      q.x = pk2(acc[t][0] + bv.x, acc[t][1] + bv.y);
      q.y = pk2(acc[t][2] + bv.z, acc[t][3] + bv.w);
      *reinterpret_cast<uint2*>(dst + o0) = q;
    }
  }
}

extern "C" void kernel_launch(void* const* d_in, const int* in_sizes, int n_in,
                              void* d_out, int out_size, void* d_ws, size_t ws_size,
                              hipStream_t stream) {
  const int*   node_ids = (const int*)d_in[0];
  const int*   src   = (const int*)d_in[1];
  const int*   dst   = (const int*)d_in[2];
  const int*   etype = (const int*)d_in[3];
  const float* emb   = (const float*)d_in[4];
  const float* W1    = (const float*)d_in[5];
  const float* Ws1   = (const float*)d_in[6];
  const float* b1    = (const float*)d_in[7];
  const float* W2    = (const float*)d_in[8];
  const float* Ws2   = (const float*)d_in[9];
  const float* b2    = (const float*)d_in[10];

  // ws layout (~35 MB):
  //   h0     bf16 [NN*DD]       12.8 MB
  //   h1     bf16 [NN*DD]       12.8 MB
  //   WT     bf16 [18*DD*DD]     0.59 MB
  //   off8   i32  [NB+1]         1.6 MB
  //   deg8   i32  [NB]           1.6 MB
  //   eidx   i32  [NE]           2.4 MB
  //   bsum/bbase i32 [NCHUNK8]
  char* p = (char*)d_ws;
  unsigned short* h0 = (unsigned short*)p;  p += (size_t)NN * DD * 2;
  unsigned short* h1 = (unsigned short*)p;  p += (size_t)NN * DD * 2;
  unsigned short* WT = (unsigned short*)p;  p += (size_t)18 * DD * DD * 2;
  int* off8          = (int*)p;             p += (size_t)(NB + 1) * 4;
  int* deg8          = (int*)p;             p += (size_t)NB * 4;
  int* eidx          = (int*)p;             p += (size_t)NE * 4;
  int* bsum          = (int*)p;             p += (size_t)NCHUNK8 * 4;
  int* bbase         = (int*)p;

  const int eb = (NE + 255) / 256;
  const int tb = (NN + 127) / 128;   // 391

  // weight convert + h0 convert + CSR build over (dst,rel)
  convw_kernel<<<dim3(DD, 18), 128, 0, stream>>>(W1, Ws1, W2, Ws2, WT);
  convh_kernel<<<(NN * 16) / 256, 256, 0, stream>>>(emb, node_ids, h0);
  hipMemsetAsync(deg8, 0, (size_t)NB * 4, stream);
  hist_kernel<<<eb, 256, 0, stream>>>(dst, etype, deg8);
  bsum_kernel<<<NCHUNK8, 256, 0, stream>>>(deg8, bsum);
  bscan_kernel<<<1, 256, 0, stream>>>(bsum, bbase);
  expand_kernel<<<NCHUNK8, 256, 0, stream>>>(deg8, bbase, off8);
  fill_kernel<<<eb, 256, 0, stream>>>(src, dst, etype, deg8, eidx);

  // fused layers (no s materialization)
  layer_kernel<0><<<tb, 512, 0, stream>>>(h0, off8, eidx, WT, b1, h1);
  layer_kernel<1><<<tb, 512, 0, stream>>>(h1, off8, eidx, WT + (size_t)9 * DD * DD, b2, (float*)d_out);
}